// Round 5
// baseline (1012.443 us; speedup 1.0000x reference)
//
#include <hip/hip_runtime.h>
#include <cstddef>
#include <cstdint>

#define N_IN  128
#define N_HID 128
#define N_OUT 64
#define SPAN  128   // nodes per CSR-fill bucket

typedef unsigned short ushort;
typedef unsigned int uint;
using short8 = __attribute__((ext_vector_type(8))) short;
using f32x4  = __attribute__((ext_vector_type(4))) float;

__device__ __forceinline__ ushort f2b(float f) {
  uint u = __builtin_bit_cast(uint, f);
  uint r = (u + 0x7fffu + ((u >> 16) & 1u)) >> 16;   // RNE
  return (ushort)r;
}
__device__ __forceinline__ float b2f(ushort u) {
  return __builtin_bit_cast(float, ((uint)u) << 16);
}

// ---------------- CSR build ----------------

__global__ void count_deg_kernel(const int* __restrict__ ei, int* __restrict__ deg, int E) {
  int e = blockIdx.x * 256 + threadIdx.x;
  if (e < E) atomicAdd(&deg[ei[E + e]], 1);
}

__global__ __launch_bounds__(256) void scanA_kernel(const int* __restrict__ deg,
                                                    int* __restrict__ bsum, int n) {
  int i = blockIdx.x * 256 + threadIdx.x;
  int v = (i < n) ? deg[i] : 0;
#pragma unroll
  for (int off = 32; off > 0; off >>= 1) v += __shfl_xor(v, off, 64);
  __shared__ int ws[4];
  int lane = threadIdx.x & 63, wid = threadIdx.x >> 6;
  if (lane == 0) ws[wid] = v;
  __syncthreads();
  if (threadIdx.x == 0) bsum[blockIdx.x] = ws[0] + ws[1] + ws[2] + ws[3];
}

__global__ __launch_bounds__(256) void scanB_kernel(int* __restrict__ bsum, int nb) {
  int tid = threadIdx.x;
  int c = (nb + 255) >> 8;
  int st = tid * c, en = min(st + c, nb);
  int s = 0;
  for (int i = st; i < en; ++i) s += bsum[i];
  int lane = tid & 63, wid = tid >> 6;
  int incl = s;
#pragma unroll
  for (int off = 1; off < 64; off <<= 1) {
    int t = __shfl_up(incl, off, 64);
    if (lane >= off) incl += t;
  }
  __shared__ int ws[4];
  if (lane == 63) ws[wid] = incl;
  __syncthreads();
  int wbase = 0;
  for (int w = 0; w < wid; ++w) wbase += ws[w];
  int ex = wbase + incl - s;
  for (int i = st; i < en; ++i) {
    int d = bsum[i];
    bsum[i] = ex;
    ex += d;
  }
}

__global__ __launch_bounds__(256) void scanC_kernel(const int* __restrict__ deg,
                                                    const int* __restrict__ bsum,
                                                    int* __restrict__ rowptr,
                                                    float* __restrict__ dis, int n) {
  int i = blockIdx.x * 256 + threadIdx.x;
  int d = (i < n) ? deg[i] : 0;
  int lane = threadIdx.x & 63, wid = threadIdx.x >> 6;
  int incl = d;
#pragma unroll
  for (int off = 1; off < 64; off <<= 1) {
    int t = __shfl_up(incl, off, 64);
    if (lane >= off) incl += t;
  }
  __shared__ int ws[4];
  if (lane == 63) ws[wid] = incl;
  __syncthreads();
  int wbase = 0;
  for (int w = 0; w < wid; ++w) wbase += ws[w];
  int ex = bsum[blockIdx.x] + wbase + incl - d;
  if (i < n) {
    rowptr[i] = ex;
    dis[i] = (d > 0) ? rsqrtf((float)d) : 0.0f;
    if (i == n - 1) rowptr[n] = ex + d;
  }
}

// bucket cursor init: bucket b's staging base = rowptr[b*SPAN]
__global__ __launch_bounds__(512) void binit_kernel(const int* __restrict__ rowptr,
                                                    int* __restrict__ bcursor, int nbuck, int n) {
  int b = blockIdx.x * 512 + threadIdx.x;
  if (b < nbuck) bcursor[b] = rowptr[min(b * SPAN, n)];
}

// phase A: coarse scatter into dst-range buckets. color-striped so all writers of a
// bucket land on one XCD (bid%8 round-robin heuristic) -> lines assemble in its L2.
__global__ __launch_bounds__(256) void bucketA_kernel(const int* __restrict__ ei,
                                                      int* __restrict__ bcursor,
                                                      int2* __restrict__ stage,
                                                      int E, int nchunks) {
  int color = blockIdx.x & 7;
  int stride = nchunks * 256;
  for (int e = (blockIdx.x >> 3) * 256 + threadIdx.x; e < E; e += stride) {
    int d = ei[E + e];
    int b = d >> 7;                    // SPAN = 128
    if ((b & 7) == color) {
      int s = ei[e];
      int pos = atomicAdd(&bcursor[b], 1);
      stage[pos] = make_int2(s, d);
    }
  }
}

// phase B: one block per bucket; LDS cursors; fine scatter into block-owned region.
__global__ __launch_bounds__(256) void bucketB_kernel(const int2* __restrict__ stage,
                                                      const int* __restrict__ rowptr,
                                                      int* __restrict__ colidx, int n) {
  __shared__ int cur[SPAN];
  int base = blockIdx.x * SPAN;
  int hi = min(base + SPAN, n);
  if (threadIdx.x < SPAN && base + threadIdx.x < n)
    cur[threadIdx.x] = rowptr[base + threadIdx.x];
  __syncthreads();
  int estart = rowptr[base];
  int eend = rowptr[hi];
  for (int t = estart + threadIdx.x; t < eend; t += 256) {
    int2 p = stage[t];
    int pos = atomicAdd(&cur[p.y - base], 1);
    colidx[pos] = p.x;
  }
}

// ---------------- fp32 -> bf16 convert (plain + dis-scaled copies) ----------------

__global__ __launch_bounds__(256) void cvt_bf16_kernel(const float* __restrict__ in,
                                                       ushort* __restrict__ xb,
                                                       ushort* __restrict__ xs,
                                                       const float* __restrict__ dis, int n4) {
  int i = blockIdx.x * 256 + threadIdx.x;
  if (i >= n4) return;
  float4 v = reinterpret_cast<const float4*>(in)[i];
  float d = dis[i >> 5];   // 32 float4 per 128-wide row
  ushort4 o, os;
  o.x = f2b(v.x); o.y = f2b(v.y); o.z = f2b(v.z); o.w = f2b(v.w);
  os.x = f2b(v.x * d); os.y = f2b(v.y * d); os.z = f2b(v.z * d); os.w = f2b(v.w * d);
  reinterpret_cast<ushort4*>(xb)[i] = o;
  reinterpret_cast<ushort4*>(xs)[i] = os;
}

// ---------------- W pack into MFMA B-fragment order ----------------
// pw[(k*4+kk)*CT + ct][lane][j] = W[k][kk*32 + (lane>>4)*8 + j][ct*16 + (lane&15)]

template <int FOUT>
__global__ __launch_bounds__(256) void pack_w_kernel(const float* __restrict__ W,
                                                     ushort* __restrict__ pw) {
  constexpr int CT = FOUT / 16;
  int t = blockIdx.x * 256 + threadIdx.x;
  if (t >= 4 * 4 * CT * 64) return;
  int lane = t & 63;
  int g = t >> 6;
  int ct = g % CT;
  int kk = (g / CT) % 4;
  int k  = g / (CT * 4);
  int col = ct * 16 + (lane & 15);
  int krow0 = kk * 32 + (lane >> 4) * 8;
  ushort* dst = pw + (size_t)t * 8;
  const float* src = W + ((size_t)k * 128 + krow0) * FOUT + col;
#pragma unroll
  for (int j = 0; j < 8; ++j) dst[j] = f2b(src[(size_t)j * FOUT]);
}

// ---------------- sparse propagation ----------------
// ins = dis-scaled input features (bf16). s_i = sum_{e in row} ins[src_e]
// out_i  = -dis_i * s_i                (sub == nullptr)
// out_i  = 2*(-dis_i*s_i) - sub_i      (sub != nullptr)
// outs_i = dis_i * out_i   (scaled copy for the next prop; optional)
// TWO waves per node (64 features each, 128B gathers) -> 2x wave parallelism;
// unroll x8 -> 8 outstanding gathers per wave.

__global__ __launch_bounds__(256) void prop_kernel(
    const ushort* __restrict__ ins, const ushort* __restrict__ sub,
    ushort* __restrict__ out, ushort* __restrict__ outs,
    const int* __restrict__ rowptr, const int* __restrict__ colidx,
    const float* __restrict__ dis, int n) {
  int node = blockIdx.x * 2 + (threadIdx.x >> 7);
  if (node >= n) return;
  int f = threadIdx.x & 127;
  int s = rowptr[node];
  int e = rowptr[node + 1];
  size_t ro = ((size_t)node << 7) + f;
  float a = 0.f;
  int i = s;
  for (; i + 8 <= e; i += 8) {
    int c[8];
#pragma unroll
    for (int j = 0; j < 8; ++j) c[j] = colidx[i + j];
    ushort v[8];
#pragma unroll
    for (int j = 0; j < 8; ++j) v[j] = ins[((size_t)c[j] << 7) + f];
#pragma unroll
    for (int j = 0; j < 8; ++j) a += b2f(v[j]);
  }
  if (i + 4 <= e) {
    int c[4];
#pragma unroll
    for (int j = 0; j < 4; ++j) c[j] = colidx[i + j];
    ushort v[4];
#pragma unroll
    for (int j = 0; j < 4; ++j) v[j] = ins[((size_t)c[j] << 7) + f];
#pragma unroll
    for (int j = 0; j < 4; ++j) a += b2f(v[j]);
    i += 4;
  }
  for (; i < e; ++i) a += b2f(ins[((size_t)colidx[i] << 7) + f]);

  float dn = dis[node];
  float sc = -dn;
  float r;
  if (sub != nullptr) r = fmaf(2.f * sc, a, -b2f(sub[ro]));
  else                r = sc * a;
  out[ro] = f2b(r);
  if (outs != nullptr) outs[ro] = f2b(r * dn);
}

// ---------------- MFMA Chebyshev GEMM ----------------
// out = epilogue( [A0|A1|A2|A3] @ packedW + bias ), A*: [n,128] bf16.
// 2 waves/block, each wave does 2 row-tiles of 16 (32 rows) -> B-frag reused 2x.
// D mapping: col = lane&15, row = (lane>>4)*4 + reg.
// FUSE_LSM (FOUT=64 only): wave holds full 64-col rows; log-softmax in-register.

template <int FOUT, bool RELU, bool OUT_BF16, bool WRITE_SCALED, bool FUSE_LSM>
__global__ __launch_bounds__(128) void mfma_gemm_kernel(
    const ushort* __restrict__ A0, const ushort* __restrict__ A1,
    const ushort* __restrict__ A2, const ushort* __restrict__ A3,
    const ushort* __restrict__ pw, const float* __restrict__ bias,
    void* __restrict__ outv, ushort* __restrict__ outs,
    const float* __restrict__ dis, int n) {
  constexpr int CT = FOUT / 16;
  int wid = threadIdx.x >> 6;
  int lane = threadIdx.x & 63;
  int rbase = (blockIdx.x * 2 + wid) * 32;
  if (rbase >= n) return;                 // n % 16 == 0
  bool t1ok = (rbase + 16) < n;
  const ushort* Ap[4] = {A0, A1, A2, A3};
  f32x4 acc[2][CT];
#pragma unroll
  for (int t = 0; t < 2; ++t)
#pragma unroll
    for (int c = 0; c < CT; ++c) acc[t][c] = (f32x4){0.f, 0.f, 0.f, 0.f};
  size_t aoff = (size_t)(rbase + (lane & 15)) * 128 + (lane >> 4) * 8;
#pragma unroll
  for (int k = 0; k < 4; ++k) {
    const ushort* A = Ap[k] + aoff;
#pragma unroll
    for (int kk = 0; kk < 4; ++kk) {
      short8 a0 = *reinterpret_cast<const short8*>(A + kk * 32);
      short8 a1 = {};
      if (t1ok) a1 = *reinterpret_cast<const short8*>(A + 16 * 128 + kk * 32);
      const ushort* B = pw + ((size_t)((k * 4 + kk) * CT) * 64 + lane) * 8;
#pragma unroll
      for (int c = 0; c < CT; ++c) {
        short8 b = *reinterpret_cast<const short8*>(B + (size_t)c * 64 * 8);
        acc[0][c] = __builtin_amdgcn_mfma_f32_16x16x32_bf16(a0, b, acc[0][c], 0, 0, 0);
        acc[1][c] = __builtin_amdgcn_mfma_f32_16x16x32_bf16(a1, b, acc[1][c], 0, 0, 0);
      }
    }
  }
  int colb = lane & 15;
  int rsub = (lane >> 4) * 4;
#pragma unroll
  for (int t = 0; t < 2; ++t) {
    int row0 = rbase + t * 16;
    if (row0 >= n) continue;
    if (FUSE_LSM) {
#pragma unroll
      for (int r = 0; r < 4; ++r) {
        int row = row0 + rsub + r;
        float v[CT];
        float m = -1e30f;
#pragma unroll
        for (int c = 0; c < CT; ++c) {
          v[c] = acc[t][c][r] + bias[c * 16 + colb];
          m = fmaxf(m, v[c]);
        }
#pragma unroll
        for (int off = 1; off < 16; off <<= 1) m = fmaxf(m, __shfl_xor(m, off, 64));
        float s = 0.f;
#pragma unroll
        for (int c = 0; c < CT; ++c) s += __expf(v[c] - m);
#pragma unroll
        for (int off = 1; off < 16; off <<= 1) s += __shfl_xor(s, off, 64);
        float ls = logf(s) + m;
#pragma unroll
        for (int c = 0; c < CT; ++c)
          reinterpret_cast<float*>(outv)[(size_t)row * FOUT + c * 16 + colb] = v[c] - ls;
      }
    } else {
#pragma unroll
      for (int c = 0; c < CT; ++c) {
        int col = c * 16 + colb;
        float bv = bias[col];
#pragma unroll
        for (int r = 0; r < 4; ++r) {
          int row = row0 + rsub + r;
          float v = acc[t][c][r] + bv;
          if (RELU) v = fmaxf(v, 0.f);
          size_t oi = (size_t)row * FOUT + col;
          if (OUT_BF16) reinterpret_cast<ushort*>(outv)[oi] = f2b(v);
          else          reinterpret_cast<float*>(outv)[oi] = v;
          if (WRITE_SCALED) outs[oi] = f2b(v * dis[row]);
        }
      }
    }
  }
}

// ---------------- launcher ----------------

extern "C" void kernel_launch(void* const* d_in, const int* in_sizes, int n_in,
                              void* d_out, int out_size, void* d_ws, size_t ws_size,
                              hipStream_t stream) {
  const float* x  = (const float*)d_in[0];
  const int*   ei = (const int*)d_in[1];
  const float* W1 = (const float*)d_in[2];
  const float* b1 = (const float*)d_in[3];
  const float* W2 = (const float*)d_in[4];
  const float* b2 = (const float*)d_in[5];
  float* out = (float*)d_out;

  const int N = in_sizes[0] / N_IN;
  const int E = in_sizes[1] / 2;
  const int NB = (N + 255) / 256;
  const int NBUCK = (N + SPAN - 1) / SPAN;

  char* base = (char*)d_ws;
  size_t off = 0;
  auto alloc = [&](size_t bytes) -> void* {
    void* p = base + off;
    off = (off + bytes + 255) & ~(size_t)255;
    return p;
  };
  int*    deg     = (int*)alloc((size_t)N * 4);
  int*    rowptr  = (int*)alloc((size_t)(N + 1) * 4);
  int*    bsum    = (int*)alloc((size_t)NB * 4);
  int*    bcursor = (int*)alloc((size_t)NBUCK * 4);
  int*    colidx  = (int*)alloc((size_t)E * 4);
  int2*   stage   = (int2*)alloc((size_t)E * 8);
  float*  dis     = (float*)alloc((size_t)N * 4);
  size_t  fsz     = (size_t)N * N_IN * 2;
  ushort* S1 = (ushort*)alloc(fsz);
  ushort* S2 = (ushort*)alloc(fsz);
  ushort* S3 = (ushort*)alloc(fsz);
  ushort* S4 = (ushort*)alloc(fsz);
  ushort* S5 = (ushort*)alloc(fsz);
  ushort* S6 = (ushort*)alloc(fsz);
  ushort* pw1 = (ushort*)alloc((size_t)4 * N_IN * N_HID * 2);
  ushort* pw2 = (ushort*)alloc((size_t)4 * N_HID * N_OUT * 2);

  // buffer aliases (lifetime-disjoint, stream-ordered)
  ushort *xb = S1, *xs = S2, *T1 = S3, *T1s = S4, *T2 = S5;
  ushort *T2s = S2, *T3 = S4;                 // xs dead after prop1, T1s after prop2
  ushort *H = S6, *Hs = S2;                   // T2s dead after prop3
  ushort *U1 = S1, *U1s = S3, *U2 = S4, *U2s = S5, *U3 = S3;

  hipMemsetAsync(deg, 0, (size_t)N * 4, stream);
  count_deg_kernel<<<(E + 255) / 256, 256, 0, stream>>>(ei, deg, E);
  scanA_kernel<<<NB, 256, 0, stream>>>(deg, bsum, N);
  scanB_kernel<<<1, 256, 0, stream>>>(bsum, NB);
  scanC_kernel<<<NB, 256, 0, stream>>>(deg, bsum, rowptr, dis, N);
  binit_kernel<<<(NBUCK + 511) / 512, 512, 0, stream>>>(rowptr, bcursor, NBUCK, N);
  const int ACHUNKS = 128;
  bucketA_kernel<<<ACHUNKS * 8, 256, 0, stream>>>(ei, bcursor, stage, E, ACHUNKS);
  bucketB_kernel<<<NBUCK, 256, 0, stream>>>(stage, rowptr, colidx, N);

  int n4 = N * N_IN / 4;
  cvt_bf16_kernel<<<(n4 + 255) / 256, 256, 0, stream>>>(x, xb, xs, dis, n4);
  pack_w_kernel<N_HID><<<(4 * 4 * (N_HID / 16) * 64 + 255) / 256, 256, 0, stream>>>(W1, pw1);
  pack_w_kernel<N_OUT><<<(4 * 4 * (N_OUT / 16) * 64 + 255) / 256, 256, 0, stream>>>(W2, pw2);

  int pgrid = (N + 1) / 2;
  int ggrid = (N + 63) / 64;
  // layer 1: Tx0 = x
  prop_kernel<<<pgrid, 256, 0, stream>>>(xs,  nullptr, T1, T1s, rowptr, colidx, dis, N);
  prop_kernel<<<pgrid, 256, 0, stream>>>(T1s, xb,      T2, T2s, rowptr, colidx, dis, N);
  prop_kernel<<<pgrid, 256, 0, stream>>>(T2s, T1,      T3, nullptr, rowptr, colidx, dis, N);
  mfma_gemm_kernel<N_HID, true, true, true, false><<<ggrid, 128, 0, stream>>>(
      xb, T1, T2, T3, pw1, b1, H, Hs, dis, N);
  // layer 2: Tx0 = H
  prop_kernel<<<pgrid, 256, 0, stream>>>(Hs,  nullptr, U1, U1s, rowptr, colidx, dis, N);
  prop_kernel<<<pgrid, 256, 0, stream>>>(U1s, H,       U2, U2s, rowptr, colidx, dis, N);
  prop_kernel<<<pgrid, 256, 0, stream>>>(U2s, U1,      U3, nullptr, rowptr, colidx, dis, N);
  mfma_gemm_kernel<N_OUT, false, false, false, true><<<ggrid, 128, 0, stream>>>(
      H, U1, U2, U3, pw2, b2, out, nullptr, dis, N);
}

// Round 6
// 895.001 us; speedup vs baseline: 1.1312x; 1.1312x over previous
//
#include <hip/hip_runtime.h>
#include <cstddef>
#include <cstdint>

#define N_IN  128
#define N_HID 128
#define N_OUT 64

typedef unsigned short ushort;
typedef unsigned int uint;
using short8 = __attribute__((ext_vector_type(8))) short;
using f32x4  = __attribute__((ext_vector_type(4))) float;

__device__ __forceinline__ ushort f2b(float f) {
  uint u = __builtin_bit_cast(uint, f);
  uint r = (u + 0x7fffu + ((u >> 16) & 1u)) >> 16;   // RNE
  return (ushort)r;
}
__device__ __forceinline__ float b2f(ushort u) {
  return __builtin_bit_cast(float, ((uint)u) << 16);
}

// ================= CSR build =================

__global__ void count_deg_kernel(const int* __restrict__ ei, int* __restrict__ deg, int E) {
  int e = blockIdx.x * 256 + threadIdx.x;
  if (e < E) atomicAdd(&deg[ei[E + e]], 1);
}

__global__ __launch_bounds__(256) void scanA_kernel(const int* __restrict__ deg,
                                                    int* __restrict__ bsum, int n) {
  int i = blockIdx.x * 256 + threadIdx.x;
  int v = (i < n) ? deg[i] : 0;
#pragma unroll
  for (int off = 32; off > 0; off >>= 1) v += __shfl_xor(v, off, 64);
  __shared__ int ws[4];
  int lane = threadIdx.x & 63, wid = threadIdx.x >> 6;
  if (lane == 0) ws[wid] = v;
  __syncthreads();
  if (threadIdx.x == 0) bsum[blockIdx.x] = ws[0] + ws[1] + ws[2] + ws[3];
}

__global__ __launch_bounds__(256) void scanB_kernel(int* __restrict__ bsum, int nb) {
  int tid = threadIdx.x;
  int c = (nb + 255) >> 8;
  int st = tid * c, en = min(st + c, nb);
  int s = 0;
  for (int i = st; i < en; ++i) s += bsum[i];
  int lane = tid & 63, wid = tid >> 6;
  int incl = s;
#pragma unroll
  for (int off = 1; off < 64; off <<= 1) {
    int t = __shfl_up(incl, off, 64);
    if (lane >= off) incl += t;
  }
  __shared__ int ws[4];
  if (lane == 63) ws[wid] = incl;
  __syncthreads();
  int wbase = 0;
  for (int w = 0; w < wid; ++w) wbase += ws[w];
  int ex = wbase + incl - s;
  for (int i = st; i < en; ++i) {
    int d = bsum[i];
    bsum[i] = ex;
    ex += d;
  }
}

__global__ __launch_bounds__(256) void scanC_kernel(const int* __restrict__ deg,
                                                    const int* __restrict__ bsum,
                                                    int* __restrict__ rowptr,
                                                    float* __restrict__ dis, int n) {
  int i = blockIdx.x * 256 + threadIdx.x;
  int d = (i < n) ? deg[i] : 0;
  int lane = threadIdx.x & 63, wid = threadIdx.x >> 6;
  int incl = d;
#pragma unroll
  for (int off = 1; off < 64; off <<= 1) {
    int t = __shfl_up(incl, off, 64);
    if (lane >= off) incl += t;
  }
  __shared__ int ws[4];
  if (lane == 63) ws[wid] = incl;
  __syncthreads();
  int wbase = 0;
  for (int w = 0; w < wid; ++w) wbase += ws[w];
  int ex = bsum[blockIdx.x] + wbase + incl - d;
  if (i < n) {
    rowptr[i] = ex;
    dis[i] = (d > 0) ? rsqrtf((float)d) : 0.0f;
    if (i == n - 1) rowptr[n] = ex + d;
  }
}

// simple scattered fill (R4 version — bucketing regressed, reverted)
__global__ void fill_csr_kernel(const int* __restrict__ ei, int* __restrict__ cursor,
                                int* __restrict__ colidx, int E) {
  int e = blockIdx.x * 256 + threadIdx.x;
  if (e >= E) return;
  int s = ei[e];
  int d = ei[E + e];
  int pos = atomicAdd(&cursor[d], 1);
  colidx[pos] = s;
}

// ================= fp32 -> bf16 convert into tiled [fb][node][16] layout =================

__global__ __launch_bounds__(256) void cvt_bf16_kernel(const float* __restrict__ in,
                                                       ushort* __restrict__ xb,
                                                       ushort* __restrict__ xs,
                                                       const float* __restrict__ dis,
                                                       int n, int n4) {
  int i = blockIdx.x * 256 + threadIdx.x;
  if (i >= n4) return;
  int node = i >> 5;       // 32 float4 per 128-wide row
  int fg = i & 31;         // feature group of 4
  float4 v = reinterpret_cast<const float4*>(in)[i];
  float d = dis[node];
  ushort4 o, os;
  o.x = f2b(v.x); o.y = f2b(v.y); o.z = f2b(v.z); o.w = f2b(v.w);
  os.x = f2b(v.x * d); os.y = f2b(v.y * d); os.z = f2b(v.z * d); os.w = f2b(v.w * d);
  size_t dst = ((size_t)(fg >> 2) * n + node) * 16 + (fg & 3) * 4;  // fb = fg>>2
  *reinterpret_cast<ushort4*>(xb + dst) = o;
  *reinterpret_cast<ushort4*>(xs + dst) = os;
}

// ================= W pack into MFMA B-fragment order =================
// pw[(k*4+kk)*CT + ct][lane][j] = W[k][kk*32 + (lane>>4)*8 + j][ct*16 + (lane&15)]

template <int FOUT>
__global__ __launch_bounds__(256) void pack_w_kernel(const float* __restrict__ W,
                                                     ushort* __restrict__ pw) {
  constexpr int CT = FOUT / 16;
  int t = blockIdx.x * 256 + threadIdx.x;
  if (t >= 4 * 4 * CT * 64) return;
  int lane = t & 63;
  int g = t >> 6;
  int ct = g % CT;
  int kk = (g / CT) % 4;
  int k  = g / (CT * 4);
  int col = ct * 16 + (lane & 15);
  int krow0 = kk * 32 + (lane >> 4) * 8;
  ushort* dst = pw + (size_t)t * 8;
  const float* src = W + ((size_t)k * 128 + krow0) * FOUT + col;
#pragma unroll
  for (int j = 0; j < 8; ++j) dst[j] = f2b(src[(size_t)j * FOUT]);
}

// ================= sparse propagation, feature-blocked =================
// features tiled [fb][node][16], fb in [0,8). fb = blockIdx&7 -> pins each
// feature slice (1.6MB, L2-resident) to one XCD via bid%8 round-robin.
// Wave: 4 edges in parallel (16 lanes each); quarter-reduce at end.
// out_i = -dis_i * sum(ins[src])         (sub==nullptr)
// out_i = 2*(-dis_i*sum) - sub_i          (sub!=nullptr);  outs_i = dis_i*out_i

__global__ __launch_bounds__(256) void prop_kernel(
    const ushort* __restrict__ ins, const ushort* __restrict__ sub,
    ushort* __restrict__ out, ushort* __restrict__ outs,
    const int* __restrict__ rowptr, const int* __restrict__ colidx,
    const float* __restrict__ dis, int n) {
  int fb = blockIdx.x & 7;
  int node = (blockIdx.x >> 3) * 4 + (threadIdx.x >> 6);
  if (node >= n) return;
  int lane = threadIdx.x & 63;
  int q = lane >> 4;        // which of 4 parallel edges
  int f = lane & 15;        // feature within block
  const ushort* base = ins + (size_t)fb * n * 16;
  int s = rowptr[node];
  int e = rowptr[node + 1];
  float a = 0.f;
  int i = s;
  for (; i + 16 <= e; i += 16) {     // 4 chunks x 4 edges
    int c[4];
#pragma unroll
    for (int j = 0; j < 4; ++j) c[j] = colidx[i + 4 * j + q];
    ushort v[4];
#pragma unroll
    for (int j = 0; j < 4; ++j) v[j] = base[((size_t)c[j] << 4) + f];
#pragma unroll
    for (int j = 0; j < 4; ++j) a += b2f(v[j]);
  }
  for (; i + 4 <= e; i += 4)
    a += b2f(base[((size_t)colidx[i + q] << 4) + f]);
  if (i + q < e)
    a += b2f(base[((size_t)colidx[i + q] << 4) + f]);
  a += __shfl_xor(a, 32, 64);
  a += __shfl_xor(a, 16, 64);

  float dn = dis[node];
  float sc = -dn;
  size_t ro = ((size_t)fb * n + node) * 16 + f;
  float r;
  if (sub != nullptr) r = fmaf(2.f * sc, a, -b2f(sub[ro]));
  else                r = sc * a;
  if (q == 0) {
    out[ro] = f2b(r);
    if (outs != nullptr) outs[ro] = f2b(r * dn);
  }
}

// ================= MFMA Chebyshev GEMM (tiled-A inputs) =================
// out = epilogue( [A0|A1|A2|A3] @ packedW + bias ); A*: tiled [fb][n][16] bf16.
// 2 waves/block, 2 row-tiles of 16 per wave. D: col=lane&15, row=(lane>>4)*4+reg.
// FUSE_LSM (FOUT=64): in-register log-softmax, fp32 row-major output.
// WRITE_SCALED/OUT_BF16 path writes tiled bf16 (+ dis-scaled copy).

template <int FOUT, bool RELU, bool OUT_BF16, bool WRITE_SCALED, bool FUSE_LSM>
__global__ __launch_bounds__(128) void mfma_gemm_kernel(
    const ushort* __restrict__ A0, const ushort* __restrict__ A1,
    const ushort* __restrict__ A2, const ushort* __restrict__ A3,
    const ushort* __restrict__ pw, const float* __restrict__ bias,
    void* __restrict__ outv, ushort* __restrict__ outs,
    const float* __restrict__ dis, int n) {
  constexpr int CT = FOUT / 16;
  int wid = threadIdx.x >> 6;
  int lane = threadIdx.x & 63;
  int rbase = (blockIdx.x * 2 + wid) * 32;
  if (rbase >= n) return;                 // n % 16 == 0
  bool t1ok = (rbase + 16) < n;
  const ushort* Ap[4] = {A0, A1, A2, A3};
  f32x4 acc[2][CT];
#pragma unroll
  for (int t = 0; t < 2; ++t)
#pragma unroll
    for (int c = 0; c < CT; ++c) acc[t][c] = (f32x4){0.f, 0.f, 0.f, 0.f};
  int rlane = rbase + (lane & 15);
  int qh = lane >> 5;            // high bit of quarter -> fb offset within kk
  int qo = ((lane >> 4) & 1) * 8;  // 8-elem offset within 16-feature block
#pragma unroll
  for (int k = 0; k < 4; ++k) {
    const ushort* A = Ap[k];
#pragma unroll
    for (int kk = 0; kk < 4; ++kk) {
      size_t fbase = ((size_t)(2 * kk + qh) * n) << 4;
      short8 a0 = *reinterpret_cast<const short8*>(A + fbase + ((size_t)rlane << 4) + qo);
      short8 a1 = {};
      if (t1ok)
        a1 = *reinterpret_cast<const short8*>(A + fbase + ((size_t)(rlane + 16) << 4) + qo);
      const ushort* B = pw + ((size_t)((k * 4 + kk) * CT) * 64 + lane) * 8;
#pragma unroll
      for (int c = 0; c < CT; ++c) {
        short8 b = *reinterpret_cast<const short8*>(B + (size_t)c * 64 * 8);
        acc[0][c] = __builtin_amdgcn_mfma_f32_16x16x32_bf16(a0, b, acc[0][c], 0, 0, 0);
        acc[1][c] = __builtin_amdgcn_mfma_f32_16x16x32_bf16(a1, b, acc[1][c], 0, 0, 0);
      }
    }
  }
  int colb = lane & 15;
  int rsub = (lane >> 4) * 4;
#pragma unroll
  for (int t = 0; t < 2; ++t) {
    int row0 = rbase + t * 16;
    if (row0 >= n) continue;
    if (FUSE_LSM) {
#pragma unroll
      for (int r = 0; r < 4; ++r) {
        int row = row0 + rsub + r;
        float v[CT];
        float m = -1e30f;
#pragma unroll
        for (int c = 0; c < CT; ++c) {
          v[c] = acc[t][c][r] + bias[c * 16 + colb];
          m = fmaxf(m, v[c]);
        }
#pragma unroll
        for (int off = 1; off < 16; off <<= 1) m = fmaxf(m, __shfl_xor(m, off, 64));
        float s = 0.f;
#pragma unroll
        for (int c = 0; c < CT; ++c) s += __expf(v[c] - m);
#pragma unroll
        for (int off = 1; off < 16; off <<= 1) s += __shfl_xor(s, off, 64);
        float ls = logf(s) + m;
#pragma unroll
        for (int c = 0; c < CT; ++c)
          reinterpret_cast<float*>(outv)[(size_t)row * FOUT + c * 16 + colb] = v[c] - ls;
      }
    } else {
#pragma unroll
      for (int c = 0; c < CT; ++c) {
        float bv = bias[c * 16 + colb];
#pragma unroll
        for (int r = 0; r < 4; ++r) {
          int row = row0 + rsub + r;
          float v = acc[t][c][r] + bv;
          if (RELU) v = fmaxf(v, 0.f);
          size_t oi = ((size_t)c * n + row) * 16 + colb;   // tiled: fb == c (FOUT=128)
          if (OUT_BF16) reinterpret_cast<ushort*>(outv)[oi] = f2b(v);
          else          reinterpret_cast<float*>(outv)[oi] = v;
          if (WRITE_SCALED) outs[oi] = f2b(v * dis[row]);
        }
      }
    }
  }
}

// ================= launcher =================

extern "C" void kernel_launch(void* const* d_in, const int* in_sizes, int n_in,
                              void* d_out, int out_size, void* d_ws, size_t ws_size,
                              hipStream_t stream) {
  const float* x  = (const float*)d_in[0];
  const int*   ei = (const int*)d_in[1];
  const float* W1 = (const float*)d_in[2];
  const float* b1 = (const float*)d_in[3];
  const float* W2 = (const float*)d_in[4];
  const float* b2 = (const float*)d_in[5];
  float* out = (float*)d_out;

  const int N = in_sizes[0] / N_IN;
  const int E = in_sizes[1] / 2;
  const int NB = (N + 255) / 256;

  char* base = (char*)d_ws;
  size_t off = 0;
  auto alloc = [&](size_t bytes) -> void* {
    void* p = base + off;
    off = (off + bytes + 255) & ~(size_t)255;
    return p;
  };
  int*    deg    = (int*)alloc((size_t)N * 4);
  int*    rowptr = (int*)alloc((size_t)(N + 1) * 4);
  int*    cursor = (int*)alloc((size_t)N * 4);
  int*    bsum   = (int*)alloc((size_t)NB * 4);
  int*    colidx = (int*)alloc((size_t)E * 4);
  float*  dis    = (float*)alloc((size_t)N * 4);
  size_t  fsz    = (size_t)N * N_IN * 2;
  ushort* S1 = (ushort*)alloc(fsz);
  ushort* S2 = (ushort*)alloc(fsz);
  ushort* S3 = (ushort*)alloc(fsz);
  ushort* S4 = (ushort*)alloc(fsz);
  ushort* S5 = (ushort*)alloc(fsz);
  ushort* S6 = (ushort*)alloc(fsz);
  ushort* pw1 = (ushort*)alloc((size_t)4 * N_IN * N_HID * 2);
  ushort* pw2 = (ushort*)alloc((size_t)4 * N_HID * N_OUT * 2);

  // buffer aliases (lifetime-disjoint, stream-ordered)
  ushort *xb = S1, *xs = S2, *T1 = S3, *T1s = S4, *T2 = S5;
  ushort *T2s = S2, *T3 = S4;                 // xs dead after prop1, T1s after prop2
  ushort *H = S6, *Hs = S2;                   // T2s dead after prop3
  ushort *U1 = S1, *U1s = S3, *U2 = S4, *U2s = S5, *U3 = S3;

  hipMemsetAsync(deg, 0, (size_t)N * 4, stream);
  count_deg_kernel<<<(E + 255) / 256, 256, 0, stream>>>(ei, deg, E);
  scanA_kernel<<<NB, 256, 0, stream>>>(deg, bsum, N);
  scanB_kernel<<<1, 256, 0, stream>>>(bsum, NB);
  scanC_kernel<<<NB, 256, 0, stream>>>(deg, bsum, rowptr, dis, N);
  hipMemcpyAsync(cursor, rowptr, (size_t)N * 4, hipMemcpyDeviceToDevice, stream);
  fill_csr_kernel<<<(E + 255) / 256, 256, 0, stream>>>(ei, cursor, colidx, E);

  int n4 = N * N_IN / 4;
  cvt_bf16_kernel<<<(n4 + 255) / 256, 256, 0, stream>>>(x, xb, xs, dis, N, n4);
  pack_w_kernel<N_HID><<<(4 * 4 * (N_HID / 16) * 64 + 255) / 256, 256, 0, stream>>>(W1, pw1);
  pack_w_kernel<N_OUT><<<(4 * 4 * (N_OUT / 16) * 64 + 255) / 256, 256, 0, stream>>>(W2, pw2);

  int pgrid = 8 * ((N + 3) / 4);    // fb-major via blockIdx&7 -> XCD pinning
  int ggrid = (N + 63) / 64;
  // layer 1: Tx0 = x
  prop_kernel<<<pgrid, 256, 0, stream>>>(xs,  nullptr, T1, T1s, rowptr, colidx, dis, N);
  prop_kernel<<<pgrid, 256, 0, stream>>>(T1s, xb,      T2, T2s, rowptr, colidx, dis, N);
  prop_kernel<<<pgrid, 256, 0, stream>>>(T2s, T1,      T3, nullptr, rowptr, colidx, dis, N);
  mfma_gemm_kernel<N_HID, true, true, true, false><<<ggrid, 128, 0, stream>>>(
      xb, T1, T2, T3, pw1, b1, H, Hs, dis, N);
  // layer 2: Tx0 = H
  prop_kernel<<<pgrid, 256, 0, stream>>>(Hs,  nullptr, U1, U1s, rowptr, colidx, dis, N);
  prop_kernel<<<pgrid, 256, 0, stream>>>(U1s, H,       U2, U2s, rowptr, colidx, dis, N);
  prop_kernel<<<pgrid, 256, 0, stream>>>(U2s, U1,      U3, nullptr, rowptr, colidx, dis, N);
  mfma_gemm_kernel<N_OUT, false, false, false, true><<<ggrid, 128, 0, stream>>>(
      H, U1, U2, U3, pw2, b2, out, nullptr, dis, N);
}

// Round 7
// 374.461 us; speedup vs baseline: 2.7037x; 2.3901x over previous
//
#include <hip/hip_runtime.h>
#include <cstddef>
#include <cstdint>

#define N_IN  128
#define N_HID 128
#define N_OUT 64

typedef unsigned short ushort;
typedef unsigned int uint;
using short8 = __attribute__((ext_vector_type(8))) short;
using f32x4  = __attribute__((ext_vector_type(4))) float;

__device__ __forceinline__ ushort f2b(float f) {
  uint u = __builtin_bit_cast(uint, f);
  uint r = (u + 0x7fffu + ((u >> 16) & 1u)) >> 16;   // RNE
  return (ushort)r;
}
__device__ __forceinline__ float b2f(ushort u) {
  return __builtin_bit_cast(float, ((uint)u) << 16);
}

// ================= CSR build =================

__global__ void count_deg_kernel(const int* __restrict__ ei, int* __restrict__ deg, int E) {
  int e = blockIdx.x * 256 + threadIdx.x;
  if (e < E) atomicAdd(&deg[ei[E + e]], 1);
}

__global__ __launch_bounds__(256) void scanA_kernel(const int* __restrict__ deg,
                                                    int* __restrict__ bsum, int n) {
  int i = blockIdx.x * 256 + threadIdx.x;
  int v = (i < n) ? deg[i] : 0;
#pragma unroll
  for (int off = 32; off > 0; off >>= 1) v += __shfl_xor(v, off, 64);
  __shared__ int ws[4];
  int lane = threadIdx.x & 63, wid = threadIdx.x >> 6;
  if (lane == 0) ws[wid] = v;
  __syncthreads();
  if (threadIdx.x == 0) bsum[blockIdx.x] = ws[0] + ws[1] + ws[2] + ws[3];
}

__global__ __launch_bounds__(256) void scanB_kernel(int* __restrict__ bsum, int nb) {
  int tid = threadIdx.x;
  int c = (nb + 255) >> 8;
  int st = tid * c, en = min(st + c, nb);
  int s = 0;
  for (int i = st; i < en; ++i) s += bsum[i];
  int lane = tid & 63, wid = tid >> 6;
  int incl = s;
#pragma unroll
  for (int off = 1; off < 64; off <<= 1) {
    int t = __shfl_up(incl, off, 64);
    if (lane >= off) incl += t;
  }
  __shared__ int ws[4];
  if (lane == 63) ws[wid] = incl;
  __syncthreads();
  int wbase = 0;
  for (int w = 0; w < wid; ++w) wbase += ws[w];
  int ex = wbase + incl - s;
  for (int i = st; i < en; ++i) {
    int d = bsum[i];
    bsum[i] = ex;
    ex += d;
  }
}

__global__ __launch_bounds__(256) void scanC_kernel(const int* __restrict__ deg,
                                                    const int* __restrict__ bsum,
                                                    int* __restrict__ rowptr,
                                                    float* __restrict__ dis, int n) {
  int i = blockIdx.x * 256 + threadIdx.x;
  int d = (i < n) ? deg[i] : 0;
  int lane = threadIdx.x & 63, wid = threadIdx.x >> 6;
  int incl = d;
#pragma unroll
  for (int off = 1; off < 64; off <<= 1) {
    int t = __shfl_up(incl, off, 64);
    if (lane >= off) incl += t;
  }
  __shared__ int ws[4];
  if (lane == 63) ws[wid] = incl;
  __syncthreads();
  int wbase = 0;
  for (int w = 0; w < wid; ++w) wbase += ws[w];
  int ex = bsum[blockIdx.x] + wbase + incl - d;
  if (i < n) {
    rowptr[i] = ex;
    dis[i] = (d > 0) ? rsqrtf((float)d) : 0.0f;
    if (i == n - 1) rowptr[n] = ex + d;
  }
}

// (src, dis[src]) entries: 8B payload costs the same line-granular write
// amplification as 4B (measured R3 vs R4: both ~52 MB), so the weight is free.
__global__ void fill_csr_kernel(const int* __restrict__ ei, int* __restrict__ cursor,
                                int2* __restrict__ ew, const float* __restrict__ dis, int E) {
  int e = blockIdx.x * 256 + threadIdx.x;
  if (e >= E) return;
  int s = ei[e];
  int d = ei[E + e];
  int pos = atomicAdd(&cursor[d], 1);
  ew[pos] = make_int2(s, __builtin_bit_cast(int, dis[s]));
}

// ================= fp32 -> bf16 convert =================

__global__ __launch_bounds__(256) void cvt_bf16_kernel(const float* __restrict__ in,
                                                       ushort* __restrict__ xb, int n4) {
  int i = blockIdx.x * 256 + threadIdx.x;
  if (i >= n4) return;
  float4 v = reinterpret_cast<const float4*>(in)[i];
  ushort4 o;
  o.x = f2b(v.x); o.y = f2b(v.y); o.z = f2b(v.z); o.w = f2b(v.w);
  reinterpret_cast<ushort4*>(xb)[i] = o;
}

// ================= W pack into MFMA B-fragment order =================
// pw[(k*4+kk)*CT + ct][lane][j] = W[k][kk*32 + (lane>>4)*8 + j][ct*16 + (lane&15)]

template <int FOUT>
__global__ __launch_bounds__(256) void pack_w_kernel(const float* __restrict__ W,
                                                     ushort* __restrict__ pw) {
  constexpr int CT = FOUT / 16;
  int t = blockIdx.x * 256 + threadIdx.x;
  if (t >= 4 * 4 * CT * 64) return;
  int lane = t & 63;
  int g = t >> 6;
  int ct = g % CT;
  int kk = (g / CT) % 4;
  int k  = g / (CT * 4);
  int col = ct * 16 + (lane & 15);
  int krow0 = kk * 32 + (lane >> 4) * 8;
  ushort* dst = pw + (size_t)t * 8;
  const float* src = W + ((size_t)k * 128 + krow0) * FOUT + col;
#pragma unroll
  for (int j = 0; j < 8; ++j) dst[j] = f2b(src[(size_t)j * FOUT]);
}

// ================= sparse propagation =================
// out_i = -dis_i * sum_e w_e * in[src_e]          (sub==nullptr)
// out_i = 2*(-dis_i*sum) - sub_i                  (sub!=nullptr)
// TWO nodes per wave: 32 lanes/node, uint2 (4 bf16 features) per lane.
// Each gather instr fetches two full 256B rows; unroll 8 -> 16 in-flight
// gathers per wave (2x the 1-node/wave version). Clamp+zero-weight masking
// keeps the unrolled loop uniform.

__global__ __launch_bounds__(256) void prop_kernel(
    const ushort* __restrict__ in, const ushort* __restrict__ sub,
    ushort* __restrict__ out,
    const int* __restrict__ rowptr, const int2* __restrict__ ew,
    const float* __restrict__ dis, int n) {
  int node = blockIdx.x * 8 + (threadIdx.x >> 5);
  if (node >= n) return;
  int hl = threadIdx.x & 31;
  int s = rowptr[node];
  int e = rowptr[node + 1];
  size_t ro = ((size_t)node << 7) + (hl << 2);
  uint2 sv = make_uint2(0u, 0u);
  if (sub != nullptr) sv = *reinterpret_cast<const uint2*>(sub + ro);
  float a0 = 0.f, a1 = 0.f, a2 = 0.f, a3 = 0.f;
  for (int i = s; i < e; i += 8) {
    int2 p[8];
#pragma unroll
    for (int j = 0; j < 8; ++j) {
      int idx = i + j;
      p[j] = ew[idx < e ? idx : e - 1];
    }
    uint2 v[8];
#pragma unroll
    for (int j = 0; j < 8; ++j)
      v[j] = *reinterpret_cast<const uint2*>(in + ((size_t)p[j].x << 7) + (hl << 2));
#pragma unroll
    for (int j = 0; j < 8; ++j) {
      float w = (i + j < e) ? __builtin_bit_cast(float, p[j].y) : 0.f;
      a0 = fmaf(w, b2f((ushort)v[j].x), a0);
      a1 = fmaf(w, b2f((ushort)(v[j].x >> 16)), a1);
      a2 = fmaf(w, b2f((ushort)v[j].y), a2);
      a3 = fmaf(w, b2f((ushort)(v[j].y >> 16)), a3);
    }
  }
  float sc = -dis[node];
  float r0, r1, r2, r3;
  if (sub != nullptr) {
    float t = 2.f * sc;
    r0 = fmaf(t, a0, -b2f((ushort)sv.x));
    r1 = fmaf(t, a1, -b2f((ushort)(sv.x >> 16)));
    r2 = fmaf(t, a2, -b2f((ushort)sv.y));
    r3 = fmaf(t, a3, -b2f((ushort)(sv.y >> 16)));
  } else {
    r0 = sc * a0; r1 = sc * a1; r2 = sc * a2; r3 = sc * a3;
  }
  uint2 o;
  o.x = (uint)f2b(r0) | ((uint)f2b(r1) << 16);
  o.y = (uint)f2b(r2) | ((uint)f2b(r3) << 16);
  *reinterpret_cast<uint2*>(out + ro) = o;
}

// ================= MFMA Chebyshev GEMM =================
// out = epilogue( [A0|A1|A2|A3] @ packedW + bias ), A*: [n,128] bf16 row-major.
// 2 waves/block, each wave does 2 row-tiles of 16 (32 rows) -> B-frag reused 2x.
// D mapping: col = lane&15, row = (lane>>4)*4 + reg.
// FUSE_LSM (FOUT=64): wave holds full 64-col rows; log-softmax in-register.

template <int FOUT, bool RELU, bool OUT_BF16, bool FUSE_LSM>
__global__ __launch_bounds__(128) void mfma_gemm_kernel(
    const ushort* __restrict__ A0, const ushort* __restrict__ A1,
    const ushort* __restrict__ A2, const ushort* __restrict__ A3,
    const ushort* __restrict__ pw, const float* __restrict__ bias,
    void* __restrict__ outv, int n) {
  constexpr int CT = FOUT / 16;
  int wid = threadIdx.x >> 6;
  int lane = threadIdx.x & 63;
  int rbase = (blockIdx.x * 2 + wid) * 32;
  if (rbase >= n) return;                 // n % 16 == 0
  bool t1ok = (rbase + 16) < n;
  const ushort* Ap[4] = {A0, A1, A2, A3};
  f32x4 acc[2][CT];
#pragma unroll
  for (int t = 0; t < 2; ++t)
#pragma unroll
    for (int c = 0; c < CT; ++c) acc[t][c] = (f32x4){0.f, 0.f, 0.f, 0.f};
  size_t aoff = (size_t)(rbase + (lane & 15)) * 128 + (lane >> 4) * 8;
#pragma unroll
  for (int k = 0; k < 4; ++k) {
    const ushort* A = Ap[k] + aoff;
#pragma unroll
    for (int kk = 0; kk < 4; ++kk) {
      short8 a0 = *reinterpret_cast<const short8*>(A + kk * 32);
      short8 a1 = {};
      if (t1ok) a1 = *reinterpret_cast<const short8*>(A + 16 * 128 + kk * 32);
      const ushort* B = pw + ((size_t)((k * 4 + kk) * CT) * 64 + lane) * 8;
#pragma unroll
      for (int c = 0; c < CT; ++c) {
        short8 b = *reinterpret_cast<const short8*>(B + (size_t)c * 64 * 8);
        acc[0][c] = __builtin_amdgcn_mfma_f32_16x16x32_bf16(a0, b, acc[0][c], 0, 0, 0);
        acc[1][c] = __builtin_amdgcn_mfma_f32_16x16x32_bf16(a1, b, acc[1][c], 0, 0, 0);
      }
    }
  }
  int colb = lane & 15;
  int rsub = (lane >> 4) * 4;
#pragma unroll
  for (int t = 0; t < 2; ++t) {
    int row0 = rbase + t * 16;
    if (row0 >= n) continue;
    if (FUSE_LSM) {
#pragma unroll
      for (int r = 0; r < 4; ++r) {
        int row = row0 + rsub + r;
        float v[CT];
        float m = -1e30f;
#pragma unroll
        for (int c = 0; c < CT; ++c) {
          v[c] = acc[t][c][r] + bias[c * 16 + colb];
          m = fmaxf(m, v[c]);
        }
#pragma unroll
        for (int off = 1; off < 16; off <<= 1) m = fmaxf(m, __shfl_xor(m, off, 64));
        float s = 0.f;
#pragma unroll
        for (int c = 0; c < CT; ++c) s += __expf(v[c] - m);
#pragma unroll
        for (int off = 1; off < 16; off <<= 1) s += __shfl_xor(s, off, 64);
        float ls = logf(s) + m;
#pragma unroll
        for (int c = 0; c < CT; ++c)
          reinterpret_cast<float*>(outv)[(size_t)row * FOUT + c * 16 + colb] = v[c] - ls;
      }
    } else {
#pragma unroll
      for (int c = 0; c < CT; ++c) {
        int col = c * 16 + colb;
        float bv = bias[col];
#pragma unroll
        for (int r = 0; r < 4; ++r) {
          int row = row0 + rsub + r;
          float v = acc[t][c][r] + bv;
          if (RELU) v = fmaxf(v, 0.f);
          size_t oi = (size_t)row * FOUT + col;
          if (OUT_BF16) reinterpret_cast<ushort*>(outv)[oi] = f2b(v);
          else          reinterpret_cast<float*>(outv)[oi] = v;
        }
      }
    }
  }
}

// ================= launcher =================

extern "C" void kernel_launch(void* const* d_in, const int* in_sizes, int n_in,
                              void* d_out, int out_size, void* d_ws, size_t ws_size,
                              hipStream_t stream) {
  const float* x  = (const float*)d_in[0];
  const int*   ei = (const int*)d_in[1];
  const float* W1 = (const float*)d_in[2];
  const float* b1 = (const float*)d_in[3];
  const float* W2 = (const float*)d_in[4];
  const float* b2 = (const float*)d_in[5];
  float* out = (float*)d_out;

  const int N = in_sizes[0] / N_IN;
  const int E = in_sizes[1] / 2;
  const int NB = (N + 255) / 256;

  char* base = (char*)d_ws;
  size_t off = 0;
  auto alloc = [&](size_t bytes) -> void* {
    void* p = base + off;
    off = (off + bytes + 255) & ~(size_t)255;
    return p;
  };
  int*    deg    = (int*)alloc((size_t)N * 4);
  int*    rowptr = (int*)alloc((size_t)(N + 1) * 4);
  int*    cursor = (int*)alloc((size_t)N * 4);
  int*    bsum   = (int*)alloc((size_t)NB * 4);
  int2*   ew     = (int2*)alloc((size_t)E * 8);
  float*  dis    = (float*)alloc((size_t)N * 4);
  size_t  fsz    = (size_t)N * N_IN * 2;
  ushort* S1 = (ushort*)alloc(fsz);
  ushort* S2 = (ushort*)alloc(fsz);
  ushort* S3 = (ushort*)alloc(fsz);
  ushort* S4 = (ushort*)alloc(fsz);
  ushort* S5 = (ushort*)alloc(fsz);
  ushort* pw1 = (ushort*)alloc((size_t)4 * N_IN * N_HID * 2);
  ushort* pw2 = (ushort*)alloc((size_t)4 * N_HID * N_OUT * 2);

  // buffer lifetimes: layer1 {xb,T1,T2,T3} -> GEMM1 -> H; xb dead after GEMM1.
  ushort *xb = S1, *T1 = S2, *T2 = S3, *T3 = S4, *H = S5;
  ushort *U1 = S1, *U2 = S2, *U3 = S3;   // reuse: T1 dead after U2, T2 after U3

  hipMemsetAsync(deg, 0, (size_t)N * 4, stream);
  count_deg_kernel<<<(E + 255) / 256, 256, 0, stream>>>(ei, deg, E);
  scanA_kernel<<<NB, 256, 0, stream>>>(deg, bsum, N);
  scanB_kernel<<<1, 256, 0, stream>>>(bsum, NB);
  scanC_kernel<<<NB, 256, 0, stream>>>(deg, bsum, rowptr, dis, N);
  hipMemcpyAsync(cursor, rowptr, (size_t)N * 4, hipMemcpyDeviceToDevice, stream);
  fill_csr_kernel<<<(E + 255) / 256, 256, 0, stream>>>(ei, cursor, ew, dis, E);

  int n4 = N * N_IN / 4;
  cvt_bf16_kernel<<<(n4 + 255) / 256, 256, 0, stream>>>(x, xb, n4);
  pack_w_kernel<N_HID><<<(4 * 4 * (N_HID / 16) * 64 + 255) / 256, 256, 0, stream>>>(W1, pw1);
  pack_w_kernel<N_OUT><<<(4 * 4 * (N_OUT / 16) * 64 + 255) / 256, 256, 0, stream>>>(W2, pw2);

  int pgrid = (N + 7) / 8;
  int ggrid = (N + 63) / 64;
  // layer 1: Tx0 = x
  prop_kernel<<<pgrid, 256, 0, stream>>>(xb, nullptr, T1, rowptr, ew, dis, N);
  prop_kernel<<<pgrid, 256, 0, stream>>>(T1, xb,      T2, rowptr, ew, dis, N);
  prop_kernel<<<pgrid, 256, 0, stream>>>(T2, T1,      T3, rowptr, ew, dis, N);
  mfma_gemm_kernel<N_HID, true, true, false><<<ggrid, 128, 0, stream>>>(
      xb, T1, T2, T3, pw1, b1, H, N);
  // layer 2: Tx0 = H
  prop_kernel<<<pgrid, 256, 0, stream>>>(H,  nullptr, U1, rowptr, ew, dis, N);
  prop_kernel<<<pgrid, 256, 0, stream>>>(U1, H,       U2, rowptr, ew, dis, N);
  prop_kernel<<<pgrid, 256, 0, stream>>>(U2, U1,      U3, rowptr, ew, dis, N);
  mfma_gemm_kernel<N_OUT, false, false, true><<<ggrid, 128, 0, stream>>>(
      H, U1, U2, U3, pw2, b2, out, N);
}